// Round 5
// baseline (301.490 us; speedup 1.0000x reference)
//
#include <hip/hip_runtime.h>

// KnotAttention MI355X — round 5: LDS-free main loops, TLP over prefetch.
//
// Round-4 autopsy: per-slot __syncthreads() (vmcnt(0) drain) exposed ~500cy
// of gather latency to all 4 lockstepped waves, occupancy stuck at ~2
// blocks/CU. Fix: B-fragments of mfma_16x16x32_f16 are 16 CONTIGUOUS bytes
// of one x-row -> load them straight from global (L1/L2-resident tile),
// no LDS, no barriers, free-running waves, launch_bounds(256,4) for ~16
// waves/CU. Neighbor indices pipelined one slot ahead. 3 dispatches.

#define N_NODES 100000
#define D 128
#define H 4
#define R 5
#define NPB 64
#define THREADS 256
#define NBLOCKS ((N_NODES + NPB - 1) / NPB)

typedef _Float16 half_t;
typedef __attribute__((ext_vector_type(8))) _Float16 f16x8;
typedef __attribute__((ext_vector_type(4))) float f32x4;

// ------------- prep: weights -> A-frags, x -> f16, zero sums_p --------------
__global__ void prep(const float* __restrict__ x,
                     const float* __restrict__ wq, const float* __restrict__ wk,
                     const float* __restrict__ wv,
                     half_t* __restrict__ xh, half_t* __restrict__ wph,
                     float* __restrict__ sums_p)
{
    const int bid = blockIdx.x;
    const int t = threadIdx.x;
    if (bid < 44) {
        const float* src = (bid < 4) ? (wq + bid * 4096)
                         : (bid < 24) ? (wk + (bid - 4) * 4096)
                                      : (wv + (bid - 24) * 4096);
#pragma unroll
        for (int i = 0; i < 16; ++i) {
            int p = t * 16 + i;
            int j = p & 7, ln = (p >> 3) & 63, f = p >> 9;
            int kt = f & 3, mt = f >> 2;
            int d = kt * 32 + (ln >> 4) * 8 + j;
            int ko = mt * 16 + (ln & 15);
            wph[bid * 4096 + p] = (half_t)src[d * 32 + ko];
        }
    } else {
        if (bid == 44) {
            for (int i = t; i < 1280; i += THREADS) sums_p[i] = 0.f;
        }
        const int total = N_NODES * D / 8;
        const int nb = gridDim.x - 44;
        for (int i = (bid - 44) * THREADS + t; i < total; i += nb * THREADS) {
            const float4* s = (const float4*)x + (size_t)i * 2;
            float4 a = s[0], b = s[1];
            f16x8 h8 = {(half_t)a.x, (half_t)a.y, (half_t)a.z, (half_t)a.w,
                        (half_t)b.x, (half_t)b.y, (half_t)b.z, (half_t)b.w};
            *((f16x8*)xh + i) = h8;
        }
    }
}

// ----------------------------- A-frag preload --------------------------------
__device__ __forceinline__ void load_af(int mid, const half_t* __restrict__ wph,
                                        int lane, f16x8 (&af)[8])
{
#pragma unroll
    for (int kt = 0; kt < 4; ++kt) {
        af[kt * 2]     = *(const f16x8*)(wph + ((mid * 8 + kt) * 64 + lane) * 8);
        af[kt * 2 + 1] = *(const f16x8*)(wph + ((mid * 8 + 4 + kt) * 64 + lane) * 8);
    }
}

// ----- 32(kout) x 64(node) x 128(d) projection, B direct from global --------
// B-frag for lane (l15,q), tile-row nt*16+l15: xh[src[nt]*128 + (kt*4+q)*8 ..+8]
__device__ __forceinline__ void proj_g(const f16x8 (&af)[8],
                                       const half_t* __restrict__ xh,
                                       const int (&src)[4], int q,
                                       f32x4 (&acc)[2][4])
{
#pragma unroll
    for (int mt = 0; mt < 2; ++mt)
#pragma unroll
        for (int nt = 0; nt < 4; ++nt)
            acc[mt][nt] = (f32x4){0.f, 0.f, 0.f, 0.f};
#pragma unroll
    for (int nt = 0; nt < 4; ++nt) {
        const half_t* p = xh + (size_t)src[nt] * 128 + q * 8;
#pragma unroll
        for (int kt = 0; kt < 4; ++kt) {
            f16x8 b = *(const f16x8*)(p + kt * 32);   // offset kt*64 bytes
            acc[0][nt] = __builtin_amdgcn_mfma_f32_16x16x32_f16(af[kt * 2], b, acc[0][nt], 0, 0, 0);
            acc[1][nt] = __builtin_amdgcn_mfma_f32_16x16x32_f16(af[kt * 2 + 1], b, acc[1][nt], 0, 0, 0);
        }
    }
}

// --------------------------- kernel 1: Q,K -> e, sums ------------------------
__global__ __launch_bounds__(THREADS, 4)
void knot_logits(const half_t* __restrict__ xh, const int* __restrict__ nbr,
                 const half_t* __restrict__ wph,
                 half_t* __restrict__ eh, float* __restrict__ sums_p)
{
    const int base = blockIdx.x * NPB;
    const int lane = threadIdx.x & 63;
    const int h = __builtin_amdgcn_readfirstlane((int)(threadIdx.x >> 6));
    const int l15 = lane & 15, q = lane >> 4;

    int self[4];
#pragma unroll
    for (int nt = 0; nt < 4; ++nt) {
        int node = base + nt * 16 + l15;
        self[nt] = (node >= N_NODES) ? (N_NODES - 1) : node;
    }

    f16x8 af[8];
    f32x4 qf[2][4], kf[2][4];
    load_af(h, wph, lane, af);
    proj_g(af, xh, self, q, qf);          // Q from self rows

    int src_cur[4], src_nxt[4];
#pragma unroll
    for (int nt = 0; nt < 4; ++nt) {
        src_cur[nt] = self[nt];                         // slot 0 = self
        src_nxt[nt] = nbr[self[nt] * 4 + 0];            // slot 1 prefetched
    }

#pragma unroll 1
    for (int r = 0; r < R; ++r) {
        load_af(4 + h * 5 + r, wph, lane, af);
        proj_g(af, xh, src_cur, q, kf);

        // pipeline next slot's indices (off the critical path)
        if (r < R - 1) {
#pragma unroll
            for (int nt = 0; nt < 4; ++nt) src_cur[nt] = src_nxt[nt];
            if (r < R - 2) {
#pragma unroll
                for (int nt = 0; nt < 4; ++nt)
                    src_nxt[nt] = nbr[self[nt] * 4 + (r + 1)];
            }
        }

        float esum = 0.f;
#pragma unroll
        for (int nt = 0; nt < 4; ++nt) {
            float p = 0.f;
#pragma unroll
            for (int mt = 0; mt < 2; ++mt)
#pragma unroll
                for (int j = 0; j < 4; ++j)
                    p += qf[mt][nt][j] * kf[mt][nt][j];
            p += __shfl_xor(p, 16, 64);
            p += __shfl_xor(p, 32, 64);
            int node = base + nt * 16 + l15;
            float e = (node < N_NODES) ? __expf(p * 0.17677669529663688f) : 0.f;
            if (q == 0 && node < N_NODES)
                eh[(size_t)(h * 5 + r) * N_NODES + node] = (half_t)e;
            esum += e;
        }
        esum += __shfl_xor(esum, 1, 64);
        esum += __shfl_xor(esum, 2, 64);
        esum += __shfl_xor(esum, 4, 64);
        esum += __shfl_xor(esum, 8, 64);
        if (lane == 0)
            atomicAdd(&sums_p[(h * 5 + r) * 64 + (blockIdx.x & 63)], esum);
    }
}

// --------------------------- kernel 2: V -> Z -> out -------------------------
#define VS 67
__global__ __launch_bounds__(THREADS, 4)
void knot_out(const half_t* __restrict__ xh, const int* __restrict__ nbr,
              const half_t* __restrict__ wph, const half_t* __restrict__ eh,
              const float* __restrict__ sums_p, float* __restrict__ out)
{
    __shared__ float zt[2 * 32 * VS];    // 17152 B epilogue transpose
    __shared__ float sums_s[20];
    const int base = blockIdx.x * NPB;
    const int lane = threadIdx.x & 63;
    const int h = __builtin_amdgcn_readfirstlane((int)(threadIdx.x >> 6));
    const int l15 = lane & 15, q = lane >> 4;

    // redundant per-block softmax-sum reduce (kills the reduce dispatch)
#pragma unroll
    for (int i = 0; i < 5; ++i) {
        int hr = h * 5 + i;
        float v = sums_p[hr * 64 + lane];
        v += __shfl_xor(v, 1, 64);  v += __shfl_xor(v, 2, 64);
        v += __shfl_xor(v, 4, 64);  v += __shfl_xor(v, 8, 64);
        v += __shfl_xor(v, 16, 64); v += __shfl_xor(v, 32, 64);
        if (lane == 0) sums_s[hr] = v;
    }
    __syncthreads();

    int self[4];
#pragma unroll
    for (int nt = 0; nt < 4; ++nt) {
        int node = base + nt * 16 + l15;
        self[nt] = (node >= N_NODES) ? (N_NODES - 1) : node;
    }

    f16x8 af[8];
    f32x4 z[2][4], vf[2][4];
#pragma unroll
    for (int mt = 0; mt < 2; ++mt)
#pragma unroll
        for (int nt = 0; nt < 4; ++nt)
            z[mt][nt] = (f32x4){0.f, 0.f, 0.f, 0.f};

    int src_cur[4], src_nxt[4];
#pragma unroll
    for (int nt = 0; nt < 4; ++nt) {
        src_cur[nt] = self[nt];
        src_nxt[nt] = nbr[self[nt] * 4 + 0];
    }

#pragma unroll 1
    for (int r = 0; r < R; ++r) {
        load_af(24 + h * 5 + r, wph, lane, af);
        float ev[4];
#pragma unroll
        for (int nt = 0; nt < 4; ++nt)
            ev[nt] = (float)eh[(size_t)(h * 5 + r) * N_NODES + self[nt]];
        proj_g(af, xh, src_cur, q, vf);

        if (r < R - 1) {
#pragma unroll
            for (int nt = 0; nt < 4; ++nt) src_cur[nt] = src_nxt[nt];
            if (r < R - 2) {
#pragma unroll
                for (int nt = 0; nt < 4; ++nt)
                    src_nxt[nt] = nbr[self[nt] * 4 + (r + 1)];
            }
        }

        float inv = 1.0f / sums_s[h * 5 + r];
#pragma unroll
        for (int nt = 0; nt < 4; ++nt) {
            float w = ev[nt] * inv;
#pragma unroll
            for (int mt = 0; mt < 2; ++mt)
#pragma unroll
                for (int j = 0; j < 4; ++j)
                    z[mt][nt][j] += w * vf[mt][nt][j];
        }
    }

    // ---------------- epilogue: 2 passes x 2 heads through LDS ---------------
#pragma unroll 1
    for (int pass = 0; pass < 2; ++pass) {
        __syncthreads();
        if ((h >> 1) == pass) {
#pragma unroll
            for (int mt = 0; mt < 2; ++mt)
#pragma unroll
                for (int nt = 0; nt < 4; ++nt)
#pragma unroll
                    for (int j = 0; j < 4; ++j) {
                        int v = mt * 16 + q * 4 + j;
                        zt[(h & 1) * 32 * VS + v * VS + nt * 16 + l15] = z[mt][nt][j];
                    }
        }
        __syncthreads();
        const int row = threadIdx.x >> 2;
        const int c = threadIdx.x & 3;
        if (base + row < N_NODES) {
            float* dst = out + (size_t)(base + row) * D + pass * 64 + c * 16;
#pragma unroll
            for (int i4 = 0; i4 < 4; ++i4) {
                float4 v4;
#pragma unroll
                for (int e = 0; e < 4; ++e) {
                    int col = c * 16 + i4 * 4 + e;   // 0..63
                    ((float*)&v4)[e] = zt[(col >> 5) * 32 * VS + (col & 31) * VS + row];
                }
                *(float4*)(dst + i4 * 4) = v4;
            }
        }
    }
}

// --------------------------------- launcher ---------------------------------
// ws (bytes): [0,5120) sums_p | [8192,+4e6) eh f16[20*N]
//             [4194304,+360448) wph | [4718592,+25.6e6) xh     ~30.3 MB
extern "C" void kernel_launch(void* const* d_in, const int* in_sizes, int n_in,
                              void* d_out, int out_size, void* d_ws, size_t ws_size,
                              hipStream_t stream)
{
    const float* x   = (const float*)d_in[0];
    const int*   nbr = (const int*)d_in[1];
    const float* w_q = (const float*)d_in[2];
    const float* w_k = (const float*)d_in[3];
    const float* w_v = (const float*)d_in[4];
    float* out = (float*)d_out;

    float*  sums_p = (float*)d_ws;
    half_t* eh     = (half_t*)((char*)d_ws + 8192);
    half_t* wph    = (half_t*)((char*)d_ws + 4194304);
    half_t* xh     = (half_t*)((char*)d_ws + 4718592);

    prep<<<44 + 2048, THREADS, 0, stream>>>(x, w_q, w_k, w_v, xh, wph, sums_p);
    knot_logits<<<NBLOCKS, THREADS, 0, stream>>>(xh, nbr, wph, eh, sums_p);
    knot_out<<<NBLOCKS, THREADS, 0, stream>>>(xh, nbr, wph, eh, sums_p, out);
}

// Round 6
// 190.753 us; speedup vs baseline: 1.5805x; 1.5805x over previous
//
#include <hip/hip_runtime.h>

// KnotAttention MI355X — round 6: R4's LDS-DMA structure + raw-barrier
// pipeline (s_waitcnt vmcnt(N), never 0, across s_barrier — AITER pattern).
//
// Slot protocol (per wave):
//   issue af(mat for this slot)              [+8 vmem, exact]
//   s_waitcnt vmcnt(8 or 12)  <- forces THIS slot's tile DMAs + everything
//                                older; leaves af (8) and the in-flight
//                                next-next-tile DMA (4) pending
//   s_barrier                  <- all waves' tile writes now visible
//   issue DMA(tile+2) -> buf[(t+2)%3]   [post-barrier: no read race]
//   ds_read B-frags + MFMA (compiler waits vmcnt(4) for af — prefetch lives)
// Count-critical instrs: af = exactly 8 loads, stage = exactly 4 DMAs.
// All stores/atomics deferred to kernel end; eh/nbr loads hoisted to the
// prologue (older than everything -> forced at the first wait, count-free).

#define N_NODES 100000
#define D 128
#define H 4
#define R 5
#define NPB 64
#define THREADS 256
#define NBLOCKS ((N_NODES + NPB - 1) / NPB)

typedef _Float16 half_t;
typedef __attribute__((ext_vector_type(2))) _Float16 f16x2;
typedef __attribute__((ext_vector_type(8))) _Float16 f16x8;
typedef __attribute__((ext_vector_type(4))) float f32x4;

typedef const __attribute__((address_space(1))) unsigned int* gp_t;
typedef __attribute__((address_space(3))) unsigned int* lp_t;

#define WAITVM(N) asm volatile("s_waitcnt vmcnt(" #N ")" ::: "memory")
#define BARRIER() asm volatile("s_barrier" ::: "memory")

__device__ __forceinline__ void async_copy16(const void* g, void* l) {
    __builtin_amdgcn_global_load_lds((gp_t)g, (lp_t)l, 16, 0, 0);
}

// ------------- prep: weights -> A-frags, x -> f16, zero sums_p --------------
__global__ void prep(const float* __restrict__ x,
                     const float* __restrict__ wq, const float* __restrict__ wk,
                     const float* __restrict__ wv,
                     half_t* __restrict__ xh, half_t* __restrict__ wph,
                     float* __restrict__ sums_p)
{
    const int bid = blockIdx.x;
    const int t = threadIdx.x;
    if (bid < 44) {
        const float* src = (bid < 4) ? (wq + bid * 4096)
                         : (bid < 24) ? (wk + (bid - 4) * 4096)
                                      : (wv + (bid - 24) * 4096);
#pragma unroll
        for (int i = 0; i < 16; ++i) {
            int p = t * 16 + i;
            int j = p & 7, ln = (p >> 3) & 63, f = p >> 9;
            int kt = f & 3, mt = f >> 2;
            int d = kt * 32 + (ln >> 4) * 8 + j;
            int ko = mt * 16 + (ln & 15);
            wph[bid * 4096 + p] = (half_t)src[d * 32 + ko];
        }
    } else {
        if (bid == 44) {
            for (int i = t; i < 1280; i += THREADS) sums_p[i] = 0.f;
        }
        const int total = N_NODES * D / 8;
        const int nb = gridDim.x - 44;
        for (int i = (bid - 44) * THREADS + t; i < total; i += nb * THREADS) {
            const float4* s = (const float4*)x + (size_t)i * 2;
            float4 a = s[0], b = s[1];
            f16x8 h8 = {(half_t)a.x, (half_t)a.y, (half_t)a.z, (half_t)a.w,
                        (half_t)b.x, (half_t)b.y, (half_t)b.z, (half_t)b.w};
            *((f16x8*)xh + i) = h8;
        }
    }
}

// ------------- staging: tile SLOT -> buf, exactly 4 DMA instrs --------------
template<int SLOT>
__device__ __forceinline__ void stage_slot(const half_t* __restrict__ xh,
                                           const int (&rows)[4], const int4 (&nb4)[4],
                                           int base, char* buf, int lane)
{
    const int rr = lane >> 4;
    const int c = lane & 15;
#pragma unroll
    for (int i = 0; i < 4; ++i) {
        int row = rows[i];
        int src;
        if constexpr (SLOT == 0) {
            int node = base + row;
            src = (node >= N_NODES) ? (N_NODES - 1) : node;
        } else if constexpr (SLOT == 1) src = nb4[i].x;
        else if constexpr (SLOT == 2) src = nb4[i].y;
        else if constexpr (SLOT == 3) src = nb4[i].z;
        else                          src = nb4[i].w;
        const char* g = (const char*)xh + (size_t)src * 256 + ((c ^ (row & 7)) << 4);
        async_copy16(g, buf + (row - rr) * 256);   // lds dest: uniform + lane*16
    }
}

// --------------------- A-frag preload: exactly 8 loads ----------------------
__device__ __forceinline__ void load_af(int mid, const half_t* __restrict__ wph,
                                        int lane, f16x8 (&af)[8])
{
#pragma unroll
    for (int kt = 0; kt < 4; ++kt) {
        af[kt * 2]     = *(const f16x8*)(wph + ((mid * 8 + kt) * 64 + lane) * 8);
        af[kt * 2 + 1] = *(const f16x8*)(wph + ((mid * 8 + 4 + kt) * 64 + lane) * 8);
    }
}

// ------- 32(kout) x 64(node) x 128(d) projection from LDS tile --------------
__device__ __forceinline__ void proj_mfma(const f16x8 (&af)[8], const half_t* tile,
                                          int lane, f32x4 (&acc)[2][4])
{
    const int l15 = lane & 15, q = lane >> 4;
#pragma unroll
    for (int mt = 0; mt < 2; ++mt)
#pragma unroll
        for (int nt = 0; nt < 4; ++nt)
            acc[mt][nt] = (f32x4){0.f, 0.f, 0.f, 0.f};
#pragma unroll
    for (int kt = 0; kt < 4; ++kt) {
#pragma unroll
        for (int nt = 0; nt < 4; ++nt) {
            int row = nt * 16 + l15;
            int sq = (kt * 4 + q) ^ (row & 7);
            f16x8 b = *(const f16x8*)(tile + row * 128 + sq * 8);
            acc[0][nt] = __builtin_amdgcn_mfma_f32_16x16x32_f16(af[kt * 2], b, acc[0][nt], 0, 0, 0);
            acc[1][nt] = __builtin_amdgcn_mfma_f32_16x16x32_f16(af[kt * 2 + 1], b, acc[1][nt], 0, 0, 0);
        }
    }
}

// --------------------------- kernel 1: Q,K -> e, sums ------------------------
#define LOGIT_MATH(r)                                                         \
    {   float es_ = 0.f;                                                      \
        _Pragma("unroll")                                                     \
        for (int nt = 0; nt < 4; ++nt) {                                      \
            float p = 0.f;                                                    \
            _Pragma("unroll")                                                 \
            for (int mt = 0; mt < 2; ++mt)                                    \
                _Pragma("unroll")                                             \
                for (int j = 0; j < 4; ++j)                                   \
                    p += qf[mt][nt][j] * kf[mt][nt][j];                       \
            p += __shfl_xor(p, 16, 64);                                       \
            p += __shfl_xor(p, 32, 64);                                       \
            int node = base + nt * 16 + l15;                                  \
            float e = (node < N_NODES) ? __expf(p * 0.17677669529663688f) : 0.f; \
            epk[r][nt >> 1][nt & 1] = (half_t)e;                              \
            es_ += e;                                                         \
        }                                                                     \
        es_ += __shfl_xor(es_, 1, 64); es_ += __shfl_xor(es_, 2, 64);         \
        es_ += __shfl_xor(es_, 4, 64); es_ += __shfl_xor(es_, 8, 64);         \
        esum[r] = es_;                                                        \
    }

__global__ __launch_bounds__(THREADS, 3)
void knot_logits(const half_t* __restrict__ xh, const int* __restrict__ nbr,
                 const half_t* __restrict__ wph,
                 half_t* __restrict__ eh, float* __restrict__ sums_p)
{
    __shared__ __align__(16) char smem[3 * 16384];
    char* buf0 = smem;
    char* buf1 = smem + 16384;
    char* buf2 = smem + 32768;
    const int base = blockIdx.x * NPB;
    const int lane = threadIdx.x & 63;
    const int h = __builtin_amdgcn_readfirstlane((int)(threadIdx.x >> 6));
    const int l15 = lane & 15, rr = lane >> 4;

    int rows[4]; int4 nb4[4];
#pragma unroll
    for (int i = 0; i < 4; ++i) {
        rows[i] = h * 16 + i * 4 + rr;
        int node = base + rows[i];
        if (node >= N_NODES) node = N_NODES - 1;
        nb4[i] = ((const int4*)nbr)[node];
    }
    stage_slot<0>(xh, rows, nb4, base, buf0, lane);
    stage_slot<1>(xh, rows, nb4, base, buf1, lane);

    f16x8 af[8];
    f32x4 qf[2][4], kf[2][4];
    f16x2 epk[5][2];
    float esum[5];

    // ---- slot 0: Q on tile0 ----
    load_af(h, wph, lane, af);
    WAITVM(8);                    // forces nbr, t0, t1; leaves af
    BARRIER();
    stage_slot<2>(xh, rows, nb4, base, buf2, lane);
    proj_mfma(af, (const half_t*)buf0, lane, qf);

    // ---- slot 1: K0 on tile0 ----
    load_af(4 + h * 5 + 0, wph, lane, af);
    WAITVM(12);                   // leaves t2 DMA + af
    BARRIER();
    proj_mfma(af, (const half_t*)buf0, lane, kf);
    LOGIT_MATH(0)

    // ---- slot 2: K1 on tile1 ----
    load_af(4 + h * 5 + 1, wph, lane, af);
    WAITVM(12);
    BARRIER();
    stage_slot<3>(xh, rows, nb4, base, buf0, lane);
    proj_mfma(af, (const half_t*)buf1, lane, kf);
    LOGIT_MATH(1)

    // ---- slot 3: K2 on tile2 ----
    load_af(4 + h * 5 + 2, wph, lane, af);
    WAITVM(12);                   // forces t2; leaves t3 + af
    BARRIER();
    stage_slot<4>(xh, rows, nb4, base, buf1, lane);
    proj_mfma(af, (const half_t*)buf2, lane, kf);
    LOGIT_MATH(2)

    // ---- slot 4: K3 on tile3 ----
    load_af(4 + h * 5 + 3, wph, lane, af);
    WAITVM(12);                   // forces t3; leaves t4 + af
    BARRIER();
    proj_mfma(af, (const half_t*)buf0, lane, kf);
    LOGIT_MATH(3)

    // ---- slot 5: K4 on tile4 ----
    load_af(4 + h * 5 + 4, wph, lane, af);
    WAITVM(8);                    // forces t4; leaves af
    BARRIER();
    proj_mfma(af, (const half_t*)buf1, lane, kf);
    LOGIT_MATH(4)

    // ---- deferred flush: eh stores + spread atomics ----
#pragma unroll
    for (int r = 0; r < 5; ++r) {
        if (rr == 0) {
#pragma unroll
            for (int nt = 0; nt < 4; ++nt) {
                int node = base + nt * 16 + l15;
                if (node < N_NODES)
                    eh[(size_t)(h * 5 + r) * N_NODES + node] = epk[r][nt >> 1][nt & 1];
            }
        }
        if (lane == 0)
            atomicAdd(&sums_p[(h * 5 + r) * 64 + (blockIdx.x & 63)], esum[r]);
    }
}

// --------------------------- kernel 2: V -> Z -> out -------------------------
#define VS 67
#define VACCUM(r)                                                             \
    _Pragma("unroll")                                                         \
    for (int nt = 0; nt < 4; ++nt) {                                          \
        float w = ev[r][nt] * inv[r];                                         \
        _Pragma("unroll")                                                     \
        for (int mt = 0; mt < 2; ++mt)                                        \
            _Pragma("unroll")                                                 \
            for (int j = 0; j < 4; ++j)                                       \
                z[mt][nt][j] += w * vf[mt][nt][j];                            \
    }

__global__ __launch_bounds__(THREADS, 3)
void knot_out(const half_t* __restrict__ xh, const int* __restrict__ nbr,
              const half_t* __restrict__ wph, const half_t* __restrict__ eh,
              const float* __restrict__ sums_p, float* __restrict__ out)
{
    __shared__ __align__(16) char smem[3 * 16384];
    char* buf0 = smem;
    char* buf1 = smem + 16384;
    char* buf2 = smem + 32768;
    __shared__ float sums_s[20];
    const int base = blockIdx.x * NPB;
    const int lane = threadIdx.x & 63;
    const int h = __builtin_amdgcn_readfirstlane((int)(threadIdx.x >> 6));
    const int l15 = lane & 15, rr = lane >> 4, q = rr;

    // per-block softmax-sum reduce (before any DMA; its drain is harmless)
#pragma unroll
    for (int i = 0; i < 5; ++i) {
        int hr = h * 5 + i;
        float v = sums_p[hr * 64 + lane];
        v += __shfl_xor(v, 1, 64);  v += __shfl_xor(v, 2, 64);
        v += __shfl_xor(v, 4, 64);  v += __shfl_xor(v, 8, 64);
        v += __shfl_xor(v, 16, 64); v += __shfl_xor(v, 32, 64);
        if (lane == 0) sums_s[hr] = v;
    }
    __syncthreads();

    float inv[5];
#pragma unroll
    for (int r = 0; r < 5; ++r) inv[r] = 1.0f / sums_s[h * 5 + r];

    int self[4];
#pragma unroll
    for (int nt = 0; nt < 4; ++nt) {
        int node = base + nt * 16 + l15;
        self[nt] = (node >= N_NODES) ? (N_NODES - 1) : node;
    }
    float ev[5][4];
#pragma unroll
    for (int r = 0; r < 5; ++r)
#pragma unroll
        for (int nt = 0; nt < 4; ++nt)
            ev[r][nt] = (float)eh[(size_t)(h * 5 + r) * N_NODES + self[nt]];

    int rows[4]; int4 nb4[4];
#pragma unroll
    for (int i = 0; i < 4; ++i) {
        rows[i] = h * 16 + i * 4 + rr;
        int node = base + rows[i];
        if (node >= N_NODES) node = N_NODES - 1;
        nb4[i] = ((const int4*)nbr)[node];
    }
    stage_slot<0>(xh, rows, nb4, base, buf0, lane);
    stage_slot<1>(xh, rows, nb4, base, buf1, lane);

    f16x8 af[8];
    f32x4 z[2][4], vf[2][4];
#pragma unroll
    for (int mt = 0; mt < 2; ++mt)
#pragma unroll
        for (int nt = 0; nt < 4; ++nt)
            z[mt][nt] = (f32x4){0.f, 0.f, 0.f, 0.f};

    // ---- slot 0: V0 on tile0 ----
    load_af(24 + h * 5 + 0, wph, lane, af);
    WAITVM(8);                    // forces ev, nbr, t0, t1; leaves af
    BARRIER();
    stage_slot<2>(xh, rows, nb4, base, buf2, lane);
    proj_mfma(af, (const half_t*)buf0, lane, vf);
    VACCUM(0)

    // ---- slot 1: V1 on tile1 ----
    load_af(24 + h * 5 + 1, wph, lane, af);
    WAITVM(12);                   // leaves t2 + af
    BARRIER();
    stage_slot<3>(xh, rows, nb4, base, buf0, lane);
    proj_mfma(af, (const half_t*)buf1, lane, vf);
    VACCUM(1)

    // ---- slot 2: V2 on tile2 ----
    load_af(24 + h * 5 + 2, wph, lane, af);
    WAITVM(12);                   // forces t2; leaves t3 + af
    BARRIER();
    stage_slot<4>(xh, rows, nb4, base, buf1, lane);
    proj_mfma(af, (const half_t*)buf2, lane, vf);
    VACCUM(2)

    // ---- slot 3: V3 on tile3 ----
    load_af(24 + h * 5 + 3, wph, lane, af);
    WAITVM(12);                   // forces t3; leaves t4 + af
    BARRIER();
    proj_mfma(af, (const half_t*)buf0, lane, vf);
    VACCUM(3)

    // ---- slot 4: V4 on tile4 ----
    load_af(24 + h * 5 + 4, wph, lane, af);
    WAITVM(8);                    // forces t4; leaves af
    BARRIER();
    proj_mfma(af, (const half_t*)buf1, lane, vf);
    VACCUM(4)

    // ---------------- epilogue: 2 passes x 2 heads through LDS ---------------
    float* zt = (float*)smem;
#pragma unroll 1
    for (int pass = 0; pass < 2; ++pass) {
        __syncthreads();
        if ((h >> 1) == pass) {
#pragma unroll
            for (int mt = 0; mt < 2; ++mt)
#pragma unroll
                for (int nt = 0; nt < 4; ++nt)
#pragma unroll
                    for (int j = 0; j < 4; ++j) {
                        int v = mt * 16 + q * 4 + j;
                        zt[(h & 1) * 32 * VS + v * VS + nt * 16 + l15] = z[mt][nt][j];
                    }
        }
        __syncthreads();
        const int row = threadIdx.x >> 2;
        const int c = threadIdx.x & 3;
        if (base + row < N_NODES) {
            float* dst = out + (size_t)(base + row) * D + pass * 64 + c * 16;
#pragma unroll
            for (int i4 = 0; i4 < 4; ++i4) {
                float4 v4;
#pragma unroll
                for (int e = 0; e < 4; ++e) {
                    int col = c * 16 + i4 * 4 + e;
                    ((float*)&v4)[e] = zt[(col >> 5) * 32 * VS + (col & 31) * VS + row];
                }
                *(float4*)(dst + i4 * 4) = v4;
            }
        }
    }
}

// --------------------------------- launcher ---------------------------------
// ws (bytes): [0,5120) sums_p | [8192,+4e6) eh f16[20*N]
//             [4194304,+360448) wph | [4718592,+25.6e6) xh     ~30.3 MB
extern "C" void kernel_launch(void* const* d_in, const int* in_sizes, int n_in,
                              void* d_out, int out_size, void* d_ws, size_t ws_size,
                              hipStream_t stream)
{
    const float* x   = (const float*)d_in[0];
    const int*   nbr = (const int*)d_in[1];
    const float* w_q = (const float*)d_in[2];
    const float* w_k = (const float*)d_in[3];
    const float* w_v = (const float*)d_in[4];
    float* out = (float*)d_out;

    float*  sums_p = (float*)d_ws;
    half_t* eh     = (half_t*)((char*)d_ws + 8192);
    half_t* wph    = (half_t*)((char*)d_ws + 4194304);
    half_t* xh     = (half_t*)((char*)d_ws + 4718592);

    prep<<<44 + 2048, THREADS, 0, stream>>>(x, w_q, w_k, w_v, xh, wph, sums_p);
    knot_logits<<<NBLOCKS, THREADS, 0, stream>>>(xh, nbr, wph, eh, sums_p);
    knot_out<<<NBLOCKS, THREADS, 0, stream>>>(xh, nbr, wph, eh, sums_p, out);
}

// Round 7
// 184.359 us; speedup vs baseline: 1.6353x; 1.0347x over previous
//
#include <hip/hip_runtime.h>

// KnotAttention MI355X — round 7: 32-node blocks, single staging burst,
// single barrier, free-running waves.
//
// R4-R6 invariant: 6 latency-separated slots per block + ~2 blocks/CU =
// ~75% stall no matter the staging scheme. Fix: block = 32 nodes so the
// ENTIRE 5-slot tile (5 x 32 rows x 256 B = 40 KB) fits in LDS at 4
// blocks/CU (16 waves/CU). All gather DMAs issue in one burst (10 per
// wave), ONE __syncthreads(), then all projections run barrier-free from
// LDS. Softmax sums reduced in registers (no LDS). 100000 = 3125*32: no
// tail anywhere.

#define N_NODES 100000
#define D 128
#define H 4
#define R 5
#define NPB 32
#define THREADS 256
#define NBLOCKS (N_NODES / NPB)   // 3125

typedef _Float16 half_t;
typedef __attribute__((ext_vector_type(2))) _Float16 f16x2;
typedef __attribute__((ext_vector_type(8))) _Float16 f16x8;
typedef __attribute__((ext_vector_type(4))) float f32x4;

typedef const __attribute__((address_space(1))) unsigned int* gp_t;
typedef __attribute__((address_space(3))) unsigned int* lp_t;

__device__ __forceinline__ void async_copy16(const void* g, void* l) {
    __builtin_amdgcn_global_load_lds((gp_t)g, (lp_t)l, 16, 0, 0);
}

// ------------- prep: weights -> A-frags, x -> f16, zero sums_p --------------
__global__ void prep(const float* __restrict__ x,
                     const float* __restrict__ wq, const float* __restrict__ wk,
                     const float* __restrict__ wv,
                     half_t* __restrict__ xh, half_t* __restrict__ wph,
                     float* __restrict__ sums_p)
{
    const int bid = blockIdx.x;
    const int t = threadIdx.x;
    if (bid < 44) {
        const float* src = (bid < 4) ? (wq + bid * 4096)
                         : (bid < 24) ? (wk + (bid - 4) * 4096)
                                      : (wv + (bid - 24) * 4096);
#pragma unroll
        for (int i = 0; i < 16; ++i) {
            int p = t * 16 + i;
            int j = p & 7, ln = (p >> 3) & 63, f = p >> 9;
            int kt = f & 3, mt = f >> 2;
            int d = kt * 32 + (ln >> 4) * 8 + j;
            int ko = mt * 16 + (ln & 15);
            wph[bid * 4096 + p] = (half_t)src[d * 32 + ko];
        }
    } else {
        if (bid == 44) {
            for (int i = t; i < 1280; i += THREADS) sums_p[i] = 0.f;
        }
        const int total = N_NODES * D / 8;
        const int nb = gridDim.x - 44;
        for (int i = (bid - 44) * THREADS + t; i < total; i += nb * THREADS) {
            const float4* s = (const float4*)x + (size_t)i * 2;
            float4 a = s[0], b = s[1];
            f16x8 h8 = {(half_t)a.x, (half_t)a.y, (half_t)a.z, (half_t)a.w,
                        (half_t)b.x, (half_t)b.y, (half_t)b.z, (half_t)b.w};
            *((f16x8*)xh + i) = h8;
        }
    }
}

// ---------- one burst: stage all 5 slot-tiles (10 DMA instrs/wave) ----------
// tile layout: slot r at r*8192; row stride 256 B; 16-B quad kq of row stored
// at kq^(row&7) (swizzle folded into the GLOBAL address; LDS dest is
// wave-uniform base + lane*16 as HW requires).
__device__ __forceinline__ void stage_all(const half_t* __restrict__ xh,
                                          const int* __restrict__ nbr,
                                          int base, char* tile, int tid)
{
    const int w = tid >> 6;
    const int lane = tid & 63;
    const int rr = lane >> 4, c = lane & 15;
    const int rowA = w * 4 + rr;          // 0..15
    const int rowB = rowA + 16;           // 16..31  (rowB&7 == rowA&7)
    const int nodeA = base + rowA;
    const int nodeB = base + rowB;
    int4 a4 = ((const int4*)nbr)[nodeA];
    int4 b4 = ((const int4*)nbr)[nodeB];
    int srcA[5] = {nodeA, a4.x, a4.y, a4.z, a4.w};
    int srcB[5] = {nodeB, b4.x, b4.y, b4.z, b4.w};
    const int sw = ((c ^ (rowA & 7)) << 4);
#pragma unroll
    for (int s = 0; s < 5; ++s) {
        const char* gA = (const char*)xh + (size_t)srcA[s] * 256 + sw;
        const char* gB = (const char*)xh + (size_t)srcB[s] * 256 + sw;
        async_copy16(gA, tile + s * 8192 + (w * 4) * 256);
        async_copy16(gB, tile + s * 8192 + (w * 4 + 16) * 256);
    }
}

// --------------------- A-frag preload: 8 loads ------------------------------
__device__ __forceinline__ void load_af(int mid, const half_t* __restrict__ wph,
                                        int lane, f16x8 (&af)[8])
{
#pragma unroll
    for (int kt = 0; kt < 4; ++kt) {
        af[kt * 2]     = *(const f16x8*)(wph + ((mid * 8 + kt) * 64 + lane) * 8);
        af[kt * 2 + 1] = *(const f16x8*)(wph + ((mid * 8 + 4 + kt) * 64 + lane) * 8);
    }
}

// -------- 32(kout) x 32(node) x 128(d) projection from LDS slot tile --------
__device__ __forceinline__ void proj32(const f16x8 (&af)[8], const half_t* tile,
                                       int lane, f32x4 (&acc)[2][2])
{
    const int l15 = lane & 15, q = lane >> 4;
#pragma unroll
    for (int mt = 0; mt < 2; ++mt)
#pragma unroll
        for (int nt = 0; nt < 2; ++nt)
            acc[mt][nt] = (f32x4){0.f, 0.f, 0.f, 0.f};
#pragma unroll
    for (int kt = 0; kt < 4; ++kt) {
#pragma unroll
        for (int nt = 0; nt < 2; ++nt) {
            int row = nt * 16 + l15;
            int sq = (kt * 4 + q) ^ (row & 7);
            f16x8 b = *(const f16x8*)(tile + row * 128 + sq * 8);
            acc[0][nt] = __builtin_amdgcn_mfma_f32_16x16x32_f16(af[kt * 2], b, acc[0][nt], 0, 0, 0);
            acc[1][nt] = __builtin_amdgcn_mfma_f32_16x16x32_f16(af[kt * 2 + 1], b, acc[1][nt], 0, 0, 0);
        }
    }
}

// --------------------------- kernel 1: Q,K -> e, sums ------------------------
__global__ __launch_bounds__(THREADS, 4)
void knot_logits(const half_t* __restrict__ xh, const int* __restrict__ nbr,
                 const half_t* __restrict__ wph,
                 half_t* __restrict__ eh, float* __restrict__ sums_p)
{
    __shared__ __align__(16) char smem[5 * 8192];   // 40960 B exactly
    const int base = blockIdx.x * NPB;
    const int lane = threadIdx.x & 63;
    const int h = __builtin_amdgcn_readfirstlane((int)(threadIdx.x >> 6));
    const int l15 = lane & 15, q = lane >> 4;

    stage_all(xh, nbr, base, smem, threadIdx.x);

    f16x8 af[8];
    load_af(h, wph, lane, af);                       // Q-weights (mat h)
    __syncthreads();                                 // the ONLY pre-compute barrier

    f32x4 qf[2][2], kf[2][2];
    proj32(af, (const half_t*)smem, lane, qf);       // Q on slot-0 tile

    f16x2 epk[5];
    float esum[5];
#pragma unroll
    for (int r = 0; r < R; ++r) {
        load_af(4 + h * 5 + r, wph, lane, af);
        proj32(af, (const half_t*)(smem + r * 8192), lane, kf);

        float es = 0.f;
#pragma unroll
        for (int nt = 0; nt < 2; ++nt) {
            float p = 0.f;
#pragma unroll
            for (int mt = 0; mt < 2; ++mt)
#pragma unroll
                for (int j = 0; j < 4; ++j)
                    p += qf[mt][nt][j] * kf[mt][nt][j];
            p += __shfl_xor(p, 16, 64);
            p += __shfl_xor(p, 32, 64);
            float e = __expf(p * 0.17677669529663688f);
            epk[r][nt] = (half_t)e;
            es += e;
        }
        es += __shfl_xor(es, 1, 64); es += __shfl_xor(es, 2, 64);
        es += __shfl_xor(es, 4, 64); es += __shfl_xor(es, 8, 64);
        esum[r] = es;    // summed over l15; q-copies identical (q==0 atomics)
    }

    // deferred flush
#pragma unroll
    for (int r = 0; r < R; ++r) {
        if (q == 0) {
#pragma unroll
            for (int nt = 0; nt < 2; ++nt)
                eh[(size_t)(h * 5 + r) * N_NODES + base + nt * 16 + l15] = epk[r][nt];
        }
        if (lane == 0)
            atomicAdd(&sums_p[(h * 5 + r) * 64 + (blockIdx.x & 63)], esum[r]);
    }
}

// --------------------------- kernel 2: V -> Z -> out -------------------------
#define ZS 132   // zt row stride in floats (16B-aligned, reads ~conflict-free)
__global__ __launch_bounds__(THREADS, 4)
void knot_out(const half_t* __restrict__ xh, const int* __restrict__ nbr,
              const half_t* __restrict__ wph, const half_t* __restrict__ eh,
              const float* __restrict__ sums_p, float* __restrict__ out)
{
    __shared__ __align__(16) char smem[5 * 8192];   // tile; reused as zt
    const int base = blockIdx.x * NPB;
    const int lane = threadIdx.x & 63;
    const int h = __builtin_amdgcn_readfirstlane((int)(threadIdx.x >> 6));
    const int l15 = lane & 15, q = lane >> 4;

    stage_all(xh, nbr, base, smem, threadIdx.x);

    // register-only softmax-sum reduce (full 64-lane xor => broadcast)
    float inv[5];
#pragma unroll
    for (int r = 0; r < R; ++r) {
        float v = sums_p[(h * 5 + r) * 64 + lane];
        v += __shfl_xor(v, 1, 64);  v += __shfl_xor(v, 2, 64);
        v += __shfl_xor(v, 4, 64);  v += __shfl_xor(v, 8, 64);
        v += __shfl_xor(v, 16, 64); v += __shfl_xor(v, 32, 64);
        inv[r] = 1.0f / v;
    }
    float ev[5][2];
#pragma unroll
    for (int r = 0; r < R; ++r)
#pragma unroll
        for (int nt = 0; nt < 2; ++nt)
            ev[r][nt] = (float)eh[(size_t)(h * 5 + r) * N_NODES + base + nt * 16 + l15];

    f16x8 af[8];
    load_af(24 + h * 5 + 0, wph, lane, af);
    __syncthreads();                                 // the ONLY pre-compute barrier

    f32x4 z[2][2], vf[2][2];
#pragma unroll
    for (int mt = 0; mt < 2; ++mt)
#pragma unroll
        for (int nt = 0; nt < 2; ++nt)
            z[mt][nt] = (f32x4){0.f, 0.f, 0.f, 0.f};

#pragma unroll
    for (int r = 0; r < R; ++r) {
        proj32(af, (const half_t*)(smem + r * 8192), lane, vf);
        if (r < R - 1) load_af(24 + h * 5 + r + 1, wph, lane, af);
#pragma unroll
        for (int nt = 0; nt < 2; ++nt) {
            float w = ev[r][nt] * inv[r];
#pragma unroll
            for (int mt = 0; mt < 2; ++mt)
#pragma unroll
                for (int j = 0; j < 4; ++j)
                    z[mt][nt][j] += w * vf[mt][nt][j];
        }
    }

    // ---- epilogue: node-major zt[32][ZS], float4 writes, coalesced reads ----
    __syncthreads();
    float* zt = (float*)smem;
#pragma unroll
    for (int mt = 0; mt < 2; ++mt)
#pragma unroll
        for (int nt = 0; nt < 2; ++nt) {
            int node = nt * 16 + l15;
            int col = h * 32 + mt * 16 + q * 4;      // j contiguous -> f32x4
            *(f32x4*)(zt + node * ZS + col) = z[mt][nt];
        }
    __syncthreads();
    {
        const int row = threadIdx.x >> 3;            // 0..31
        const int c = threadIdx.x & 7;               // 0..7
        float* dst = out + (size_t)(base + row) * D + c * 16;
        const float* srcp = zt + row * ZS + c * 16;
#pragma unroll
        for (int i4 = 0; i4 < 4; ++i4)
            *(float4*)(dst + i4 * 4) = *(const float4*)(srcp + i4 * 4);
    }
}

// --------------------------------- launcher ---------------------------------
// ws (bytes): [0,5120) sums_p | [8192,+4e6) eh f16[20*N]
//             [4194304,+360448) wph | [4718592,+25.6e6) xh     ~30.3 MB
extern "C" void kernel_launch(void* const* d_in, const int* in_sizes, int n_in,
                              void* d_out, int out_size, void* d_ws, size_t ws_size,
                              hipStream_t stream)
{
    const float* x   = (const float*)d_in[0];
    const int*   nbr = (const int*)d_in[1];
    const float* w_q = (const float*)d_in[2];
    const float* w_k = (const float*)d_in[3];
    const float* w_v = (const float*)d_in[4];
    float* out = (float*)d_out;

    float*  sums_p = (float*)d_ws;
    half_t* eh     = (half_t*)((char*)d_ws + 8192);
    half_t* wph    = (half_t*)((char*)d_ws + 4194304);
    half_t* xh     = (half_t*)((char*)d_ws + 4718592);

    prep<<<44 + 2048, THREADS, 0, stream>>>(x, w_q, w_k, w_v, xh, wph, sums_p);
    knot_logits<<<NBLOCKS, THREADS, 0, stream>>>(xh, nbr, wph, eh, sums_p);
    knot_out<<<NBLOCKS, THREADS, 0, stream>>>(xh, nbr, wph, eh, sums_p, out);
}